// Round 18
// baseline (239.710 us; speedup 1.0000x reference)
//
#include <hip/hip_runtime.h>
#include <math.h>

// ---------------------------------------------------------------------------
// GATv2 localization model, node-centric CSR attention.
// R18: launch-count surgery. gemm1 fused into bin_scatter's grid (independent
//      work, true overlap); MLP fused into attn2 (h2 stays on-chip; W staged
//      in LDS; per-node mlp wave-local). 9 launches (was 11).
// ---------------------------------------------------------------------------

typedef short s16x8 __attribute__((ext_vector_type(8)));
typedef float f32x4 __attribute__((ext_vector_type(4)));
typedef float f32x2 __attribute__((ext_vector_type(2)));

__device__ inline unsigned short f2bf(float x) {          // fp32 -> bf16 RNE
  unsigned int u = __float_as_uint(x);
  return (unsigned short)((u + 0x7fffu + ((u >> 16) & 1u)) >> 16);
}
__device__ inline float bf2f(unsigned short h) {
  return __uint_as_float(((unsigned int)h) << 16);
}
__device__ inline float bflo(unsigned int u) { return __uint_as_float(u << 16); }
__device__ inline float bfhi(unsigned int u) { return __uint_as_float(u & 0xffff0000u); }

template <int CTRL>
__device__ inline float dpp_addf(float x) {
  int y = __builtin_amdgcn_update_dpp(0, __float_as_int(x), CTRL, 0xf, 0xf, false);
  return x + __int_as_float(y);
}

// ---------------- fused: W bf16-split (blocks < WBLK) + histogram ----------
__global__ __launch_bounds__(256) void prep_hist(
    const float* __restrict__ g1wl, const float* __restrict__ g1wr,
    const float* __restrict__ res1w, const float* __restrict__ g2wl,
    const float* __restrict__ g2wr,
    unsigned short* __restrict__ hi, unsigned short* __restrict__ lo,
    const int* __restrict__ ei, const float* __restrict__ ea,
    int* __restrict__ hist, float* __restrict__ partials,
    int E, int Ep, int CH, int NB, int WBLK, int NCHUNK) {
  int t = threadIdx.x;
  if (blockIdx.x < WBLK) {
    int i = blockIdx.x * 256 + t;
    if (i >= 57344) return;
    float f;
    if (i < 8192) f = g1wl[i];
    else if (i < 16384) f = g1wr[i - 8192];
    else if (i < 24576) f = res1w[i - 16384];
    else if (i < 40960) f = g2wl[i - 24576];
    else f = g2wr[i - 40960];
    unsigned short h = f2bf(f);
    hi[i] = h;
    lo[i] = f2bf(f - bf2f(h));
    return;
  }
  __shared__ int h[256];
  __shared__ float red[256];
  int c = blockIdx.x - WBLK;
  h[t] = 0;
  float s = 0.f;
  __syncthreads();
  int s0 = c * CH, e_ = min(Ep, s0 + CH);
  for (int e = s0 + t; e < e_; e += 256) {
    int d;
    if (e < E) { d = ei[E + e]; s += ea[e]; }
    else       { d = e - E; }
    atomicAdd(&h[d >> 8], 1);
  }
  red[t] = s;
  __syncthreads();
  for (int ofs = 128; ofs > 0; ofs >>= 1) {
    if (t < ofs) red[t] += red[t + ofs];
    __syncthreads();
  }
  if (t == 0) partials[c] = red[0];
  for (int k = t; k < NB; k += 256) hist[(size_t)k * NCHUNK + c] = h[k];
}

// ---------------- scan stage 1: per-block sums -----------------------------
__global__ __launch_bounds__(1024) void scan_blocksum(
    const int* __restrict__ in, int* __restrict__ blksum, int n) {
  __shared__ int ws[16];
  int t = threadIdx.x;
  int base = blockIdx.x * 4096 + t * 4;
  int s = 0;
  if (base + 3 < n) {
    int4 v = *(const int4*)(in + base);
    s = v.x + v.y + v.z + v.w;
  } else {
    for (int i = 0; i < 4; i++) if (base + i < n) s += in[base + i];
  }
  int lane = t & 63, w = t >> 6;
#pragma unroll
  for (int ofs = 1; ofs < 64; ofs <<= 1) s += __shfl_xor(s, ofs);
  if (lane == 0) ws[w] = s;
  __syncthreads();
  if (t == 0) {
    int tot = 0;
#pragma unroll
    for (int i = 0; i < 16; i++) tot += ws[i];
    blksum[blockIdx.x] = tot;
  }
}

// ---------------- fused: blkoff scan + mean finalize + meta pad ------------
__global__ __launch_bounds__(128) void blkoff_mean(
    int* __restrict__ blksum, int nb,
    const float* __restrict__ partials, float* __restrict__ meanv, int E,
    unsigned int* __restrict__ meta, int Ep) {
  int t = threadIdx.x;
  if (t < 64) {
    int v = (t < nb) ? blksum[t] : 0;
    int orig = v;
#pragma unroll
    for (int ofs = 1; ofs < 64; ofs <<= 1) {
      int u = __shfl_up(v, ofs);
      if (t >= ofs) v += u;
    }
    if (t < nb) blksum[t] = v - orig;
    meta[Ep + t] = 0u;                      // pad: attn over-reads <= +64
  } else {
    int l = t - 64;
    float s = partials[l] + partials[l + 64] + partials[l + 128] + partials[l + 192];
#pragma unroll
    for (int ofs = 1; ofs < 64; ofs <<= 1) s += __shfl_xor(s, ofs);
    if (l == 0) meanv[0] = s / (float)E;
  }
}

__global__ __launch_bounds__(1024) void scan_out(
    const int* __restrict__ in, const int* __restrict__ blksum,
    int* __restrict__ out, int n, int total) {
  __shared__ int ws[16];
  int t = threadIdx.x;
  int base = blockIdx.x * 4096 + t * 4;
  int4 v = {0, 0, 0, 0};
  if (base + 3 < n) {
    v = *(const int4*)(in + base);
  } else {
    if (base + 0 < n) v.x = in[base + 0];
    if (base + 1 < n) v.y = in[base + 1];
    if (base + 2 < n) v.z = in[base + 2];
    if (base + 3 < n) v.w = in[base + 3];
  }
  int s = v.x + v.y + v.z + v.w;
  int lane = t & 63, w = t >> 6;
  int inc = s;
#pragma unroll
  for (int ofs = 1; ofs < 64; ofs <<= 1) {
    int u = __shfl_up(inc, ofs);
    if (lane >= ofs) inc += u;
  }
  if (lane == 63) ws[w] = inc;
  __syncthreads();
  int waveoff = 0;
#pragma unroll
  for (int i = 0; i < 16; i++) waveoff += (i < w) ? ws[i] : 0;
  int excl = blksum[blockIdx.x] + waveoff + inc - s;
  int p0 = excl, p1 = p0 + v.x, p2 = p1 + v.y, p3 = p2 + v.z;
  if (base + 0 < n) out[base + 0] = p0;
  if (base + 1 < n) out[base + 1] = p1;
  if (base + 2 < n) out[base + 2] = p2;
  if (base + 3 < n) out[base + 3] = p3;
  if (blockIdx.x == 0 && t == 0) out[n] = total;
}

// ---------------- fused: bin_scatter (blocks<NCHUNK) + gemm1 ---------------
// gemm1 (x fp32 -> 3 projections, K=64, M-tile 64) is independent of the
// scatter; fusing overlaps them. Scatter path uses off[]; gemm path Xhi/Xlo.
__global__ __launch_bounds__(256) void scatter_gemm1(
    const int* __restrict__ ei, const float* __restrict__ ea,
    const float* __restrict__ meanv, const int* __restrict__ histoff,
    unsigned int* __restrict__ binmeta, unsigned char* __restrict__ bindlo,
    int E, int Ep, int CH, int NB, int NCHUNK,
    const float* __restrict__ X,
    const unsigned short* __restrict__ Whi_all, const unsigned short* __restrict__ Wlo_all,
    const float* __restrict__ b0, unsigned short* __restrict__ o0,
    const float* __restrict__ b1, unsigned short* __restrict__ o1,
    const float* __restrict__ b2, unsigned short* __restrict__ o2,
    int N, int MB) {
  __shared__ unsigned short Xhi[64 * 64];
  __shared__ unsigned short Xlo[64 * 64];
  __shared__ int off[256];
  int t = threadIdx.x;
  if ((int)blockIdx.x < NCHUNK) {
    int c = blockIdx.x;
    for (int k = t; k < NB; k += 256) off[k] = histoff[(size_t)k * NCHUNK + c];
    __syncthreads();
    int s = c * CH, e_ = min(Ep, s + CH);
    for (int e = s + t; e < e_; e += 256) {
      int d, src; float eav;
      if (e < E) { src = ei[e]; d = ei[E + e]; eav = ea[e]; }
      else       { src = d = e - E; eav = meanv[0]; }
      int pos = atomicAdd(&off[d >> 8], 1);
      binmeta[pos] = (unsigned int)src | ((unsigned int)f2bf(eav) << 16);
      bindlo[pos] = (unsigned char)(d & 255);
    }
    return;
  }
  // ---- gemm1 path: K=64, 3 matrices, X fp32 hi/lo ----
  constexpr int K = 64;
  constexpr int KS = 2;
  int gb = blockIdx.x - NCHUNK;
  int which = gb / MB;
  int m0 = (gb % MB) * 64;
  int woff = which * 8192;
  const float* bias = (which == 0) ? b0 : (which == 1) ? b1 : b2;
  unsigned short* out = (which == 0) ? o0 : (which == 1) ? o1 : o2;
#pragma unroll
  for (int i = 0; i < 4; ++i) {
    int idx4 = t + i * 256;
    int row = idx4 / 16, k4 = idx4 % 16;
    int gm = m0 + row;
    float4 v = (gm < N) ? *(const float4*)(X + (size_t)gm * K + k4 * 4)
                        : float4{0.f, 0.f, 0.f, 0.f};
    float f[4] = {v.x, v.y, v.z, v.w};
    ushort4 h, l;
    unsigned short* hp = (unsigned short*)&h;
    unsigned short* lp = (unsigned short*)&l;
#pragma unroll
    for (int j = 0; j < 4; ++j) {
      unsigned short hb = f2bf(f[j]);
      hp[j] = hb;
      lp[j] = f2bf(f[j] - bf2f(hb));
    }
    int us = (row * K + k4 * 4) ^ ((row & 7) << 3);
    *(ushort4*)&Xhi[us] = h;
    *(ushort4*)&Xlo[us] = l;
  }
  int wv = t >> 6, lane = t & 63;
  int lr = lane & 15, kg = lane >> 4;
  s16x8 Whf[2][KS], Wlf[2][KS];
  const unsigned short* Wh = Whi_all + woff;
  const unsigned short* Wl = Wlo_all + woff;
#pragma unroll
  for (int ni = 0; ni < 2; ++ni)
#pragma unroll
    for (int ks = 0; ks < KS; ++ks) {
      int widx = (wv * 32 + ni * 16 + lr) * K + ks * 32 + kg * 8;
      Whf[ni][ks] = *(const s16x8*)(Wh + widx);
      Wlf[ni][ks] = *(const s16x8*)(Wl + widx);
    }
  __syncthreads();
  f32x4 acc[4][2] = {};
#pragma unroll
  for (int ks = 0; ks < KS; ++ks)
#pragma unroll
    for (int mi = 0; mi < 4; ++mi) {
      int r = mi * 16 + lr;
      int us = (r * K + ks * 32 + kg * 8) ^ ((r & 7) << 3);
      s16x8 ah = *(const s16x8*)&Xhi[us];
      s16x8 al = *(const s16x8*)&Xlo[us];
#pragma unroll
      for (int ni = 0; ni < 2; ++ni) {
        acc[mi][ni] = __builtin_amdgcn_mfma_f32_16x16x32_bf16(ah, Whf[ni][ks], acc[mi][ni], 0, 0, 0);
        acc[mi][ni] = __builtin_amdgcn_mfma_f32_16x16x32_bf16(ah, Wlf[ni][ks], acc[mi][ni], 0, 0, 0);
        acc[mi][ni] = __builtin_amdgcn_mfma_f32_16x16x32_bf16(al, Whf[ni][ks], acc[mi][ni], 0, 0, 0);
      }
    }
#pragma unroll
  for (int ni = 0; ni < 2; ++ni) {
    int col = wv * 32 + ni * 16 + lr;
    float bv = bias[col];
#pragma unroll
    for (int mi = 0; mi < 4; ++mi)
#pragma unroll
      for (int j = 0; j < 4; ++j) {
        int gm = m0 + mi * 16 + kg * 4 + j;
        if (gm < N) out[(size_t)gm * 128 + col] = f2bf(acc[mi][ni][j] + bv);
      }
  }
}

// ---------------- pass 2: per-bin finalize (row_ptr + in-bin sort) ---------
__global__ __launch_bounds__(256) void bin_finalize(
    const unsigned int* __restrict__ binmeta, const unsigned char* __restrict__ bindlo,
    const int* __restrict__ histoff, unsigned int* __restrict__ meta,
    int* __restrict__ row_ptr, int N, int Ep, int NCHUNK, int NB) {
  __shared__ int cntl[256];
  __shared__ int ws4[4];
  int t = threadIdx.x, k = blockIdx.x;
  int kstart = histoff[(size_t)k * NCHUNK];
  int kend = (k == NB - 1) ? Ep : histoff[(size_t)(k + 1) * NCHUNK];
  cntl[t] = 0;
  __syncthreads();
  for (int i = kstart + t; i < kend; i += 256) atomicAdd(&cntl[bindlo[i]], 1);
  __syncthreads();
  int v = cntl[t];
  int lane = t & 63, w = t >> 6;
  int inc = v;
#pragma unroll
  for (int ofs = 1; ofs < 64; ofs <<= 1) {
    int u = __shfl_up(inc, ofs);
    if (lane >= ofs) inc += u;
  }
  if (lane == 63) ws4[w] = inc;
  __syncthreads();
  int waveoff = 0;
#pragma unroll
  for (int i = 0; i < 4; i++) waveoff += (i < w) ? ws4[i] : 0;
  int base = kstart + waveoff + inc - v;
  int gd = k * 256 + t;
  if (gd < N) row_ptr[gd] = base;
  if (k == 0 && t == 0) row_ptr[N] = Ep;
  __syncthreads();
  cntl[t] = base;
  __syncthreads();
  for (int i = kstart + t; i < kend; i += 256) {
    int d = bindlo[i];
    int pos = atomicAdd(&cntl[d], 1);
    meta[pos] = binmeta[i];
  }
}

// ---------------- GEMM2 (bf16 in, M-tile 64, 2-pass) -----------------------
__global__ __launch_bounds__(256) void gemm2_mfma(
    const unsigned short* __restrict__ X,
    const unsigned short* __restrict__ Whi_all, const unsigned short* __restrict__ Wlo_all,
    const float* __restrict__ b0, unsigned short* __restrict__ o0,
    const float* __restrict__ b1, unsigned short* __restrict__ o1,
    int N) {
  constexpr int K = 128;
  constexpr int KS = 4;
  __shared__ unsigned short Xs[64 * K];
  int t = threadIdx.x;
  int m0 = blockIdx.x * 64;
  int which = blockIdx.y;
  int woff = 24576 + which * 16384;
  const float* bias = which ? b1 : b0;
  unsigned short* out = which ? o1 : o0;
#pragma unroll
  for (int i = 0; i < 4; ++i) {
    int idx8 = t + i * 256;
    int row = idx8 / 16, k8 = idx8 % 16;
    int gm = m0 + row;
    uint4 v = (gm < N) ? *(const uint4*)(X + (size_t)gm * K + k8 * 8)
                       : uint4{0u, 0u, 0u, 0u};
    int us = (row * K + k8 * 8) ^ ((row & 7) << 3);
    *(uint4*)&Xs[us] = v;
  }
  int wv = t >> 6, lane = t & 63;
  int lr = lane & 15, kg = lane >> 4;
  s16x8 Whf[2][KS], Wlf[2][KS];
  const unsigned short* Wh = Whi_all + woff;
  const unsigned short* Wl = Wlo_all + woff;
#pragma unroll
  for (int ni = 0; ni < 2; ++ni)
#pragma unroll
    for (int ks = 0; ks < KS; ++ks) {
      int widx = (wv * 32 + ni * 16 + lr) * K + ks * 32 + kg * 8;
      Whf[ni][ks] = *(const s16x8*)(Wh + widx);
      Wlf[ni][ks] = *(const s16x8*)(Wl + widx);
    }
  __syncthreads();
  f32x4 acc[4][2] = {};
#pragma unroll
  for (int ks = 0; ks < KS; ++ks)
#pragma unroll
    for (int mi = 0; mi < 4; ++mi) {
      int r = mi * 16 + lr;
      int us = (r * K + ks * 32 + kg * 8) ^ ((r & 7) << 3);
      s16x8 ah = *(const s16x8*)&Xs[us];
#pragma unroll
      for (int ni = 0; ni < 2; ++ni) {
        acc[mi][ni] = __builtin_amdgcn_mfma_f32_16x16x32_bf16(ah, Whf[ni][ks], acc[mi][ni], 0, 0, 0);
        acc[mi][ni] = __builtin_amdgcn_mfma_f32_16x16x32_bf16(ah, Wlf[ni][ks], acc[mi][ni], 0, 0, 0);
      }
    }
#pragma unroll
  for (int ni = 0; ni < 2; ++ni) {
    int col = wv * 32 + ni * 16 + lr;
    float bv = bias[col];
#pragma unroll
    for (int mi = 0; mi < 4; ++mi)
#pragma unroll
      for (int j = 0; j < 4; ++j) {
        int gm = m0 + mi * 16 + kg * 4 + j;
        if (gm < N) out[(size_t)gm * 128 + col] = f2bf(acc[mi][ni][j] + bv);
      }
  }
}

// ---------------- attention layer 1 (RED=4), stand-alone -------------------
__global__ __launch_bounds__(256) void attn1_kernel(
    const unsigned short* __restrict__ xl, const unsigned short* __restrict__ xr,
    const unsigned short* __restrict__ resid, const float* __restrict__ We,
    const float* __restrict__ att, const float* __restrict__ bias,
    const unsigned int* __restrict__ meta, const int* __restrict__ row_ptr,
    unsigned short* __restrict__ outbuf, int N) {
  int wid = threadIdx.x >> 6;
  int lane = threadIdx.x & 63;
  int n = blockIdx.x * 4 + wid;
  if (n >= N) return;
  int g = lane >> 4, li = lane & 15;
  int c = li * 8;
  f32x2 xr2[4], we2[4], at2[4];
  {
    uint4 xrr = *(const uint4*)(xr + (size_t)n * 128 + c);
    xr2[0] = f32x2{bflo(xrr.x), bfhi(xrr.x)};
    xr2[1] = f32x2{bflo(xrr.y), bfhi(xrr.y)};
    xr2[2] = f32x2{bflo(xrr.z), bfhi(xrr.z)};
    xr2[3] = f32x2{bflo(xrr.w), bfhi(xrr.w)};
  }
#pragma unroll
  for (int j = 0; j < 4; j++) {
    we2[j] = *(const f32x2*)(We + c + 2 * j);
    at2[j] = *(const f32x2*)(att + c + 2 * j) * 1.44269504088896f;
  }
  int rs = row_ptr[n], re = row_ptr[n + 1];
  float s = 0.f;
  f32x2 acc2[4] = {{0.f, 0.f}, {0.f, 0.f}, {0.f, 0.f}, {0.f, 0.f}};
  int nit = (re - rs + 3) >> 2;
  int idx = rs + g;
  bool v0 = idx < re;
  unsigned int md0 = meta[idx];
  bool v1 = idx + 4 < re;
  unsigned int md1 = meta[idx + 4];
  bool v2 = idx + 8 < re;
  unsigned int md2 = meta[idx + 8];
  uint4 raw0 = *(const uint4*)(xl + (size_t)(md0 & 0xFFFFu) * 128 + c);
  uint4 raw1 = *(const uint4*)(xl + (size_t)(md1 & 0xFFFFu) * 128 + c);
  for (int it = 0; it < nit; ++it) {
    bool v3 = idx + 12 < re;
    unsigned int md3 = meta[idx + 12];
    uint4 raw2 = *(const uint4*)(xl + (size_t)(md2 & 0xFFFFu) * 128 + c);
    f32x2 xa2[4];
    xa2[0] = f32x2{bflo(raw0.x), bfhi(raw0.x)};
    xa2[1] = f32x2{bflo(raw0.y), bfhi(raw0.y)};
    xa2[2] = f32x2{bflo(raw0.z), bfhi(raw0.z)};
    xa2[3] = f32x2{bflo(raw0.w), bfhi(raw0.w)};
    float eavf = __uint_as_float(md0 & 0xffff0000u);
    f32x2 eav2 = {eavf, eavf};
    f32x2 p2 = {0.f, 0.f};
#pragma unroll
    for (int j = 0; j < 4; j++) {
      f32x2 t = xa2[j] + xr2[j];
      t = eav2 * we2[j] + t;
      f32x2 u = t * 0.2f;
      t = __builtin_elementwise_max(t, u);
      p2 = t * at2[j] + p2;
    }
    float p = p2.x + p2.y;
    p = dpp_addf<0xB1>(p);
    p = dpp_addf<0x4E>(p);
    float ex = v0 ? exp2f(p) : 0.f;
    f32x2 ex2 = {ex, ex};
    s += ex;
#pragma unroll
    for (int j = 0; j < 4; j++) acc2[j] = ex2 * xa2[j] + acc2[j];
    idx += 4;
    v0 = v1; v1 = v2; v2 = v3;
    md0 = md1; md1 = md2; md2 = md3;
    raw0 = raw1; raw1 = raw2;
  }
#pragma unroll
  for (int ofs = 16; ofs <= 32; ofs <<= 1) {
    s += __shfl_xor(s, ofs);
#pragma unroll
    for (int j = 0; j < 4; j++) {
      acc2[j].x += __shfl_xor(acc2[j].x, ofs);
      acc2[j].y += __shfl_xor(acc2[j].y, ofs);
    }
  }
  if (g == 0) {
    float inv = 1.f / (s + 1e-16f);
    uint4 rr = *(const uint4*)(resid + (size_t)n * 128 + c);
    float rv[8];
    rv[0] = bflo(rr.x); rv[1] = bfhi(rr.x);
    rv[2] = bflo(rr.y); rv[3] = bfhi(rr.y);
    rv[4] = bflo(rr.z); rv[5] = bfhi(rr.z);
    rv[6] = bflo(rr.w); rv[7] = bfhi(rr.w);
    float o[8];
#pragma unroll
    for (int j = 0; j < 4; j++) {
      f32x2 bi = *(const f32x2*)(bias + c + 2 * j);
      o[2 * j]     = acc2[j].x * inv + bi.x + rv[2 * j];
      o[2 * j + 1] = acc2[j].y * inv + bi.y + rv[2 * j + 1];
    }
#pragma unroll
    for (int j = 0; j < 8; j++) o[j] = (o[j] > 0.f) ? o[j] : (__expf(o[j]) - 1.f);
    uint4 pk;
    pk.x = (unsigned int)f2bf(o[0]) | ((unsigned int)f2bf(o[1]) << 16);
    pk.y = (unsigned int)f2bf(o[2]) | ((unsigned int)f2bf(o[3]) << 16);
    pk.z = (unsigned int)f2bf(o[4]) | ((unsigned int)f2bf(o[5]) << 16);
    pk.w = (unsigned int)f2bf(o[6]) | ((unsigned int)f2bf(o[7]) << 16);
    *(uint4*)(outbuf + (size_t)n * 128 + c) = pk;
  }
}

// ---------------- attention layer 2 (RED=16) + fused MLP head --------------
// h2 never hits HBM: attn epilogue -> LDS -> per-wave mlp -> out[N][3].
__global__ __launch_bounds__(256) void attn2_mlp(
    const unsigned short* __restrict__ xl, const unsigned short* __restrict__ xr,
    const unsigned short* __restrict__ resid, const float* __restrict__ We,
    const float* __restrict__ att, const float* __restrict__ bias,
    const unsigned int* __restrict__ meta, const int* __restrict__ row_ptr,
    const float* __restrict__ W1, const float* __restrict__ b1,
    const float* __restrict__ W2, const float* __restrict__ b2,
    const float* __restrict__ W3, const float* __restrict__ b3,
    float* __restrict__ outp, int N) {
  __shared__ float w1t[128][33];
  __shared__ float w2t[32][33];
  __shared__ float w3t[32][4];
  __shared__ float hs[4][136];
  __shared__ float y1s[4][33];
  __shared__ float y2s[4][33];
  int t = threadIdx.x;
  int wid = t >> 6;
  int lane = t & 63;
  int n = blockIdx.x * 4 + wid;
  bool active = n < N;
  // stage mlp weights (transposed) -- overlaps with attn compute
  for (int idx = t; idx < 4096; idx += 256) {
    int oc = idx >> 7, k = idx & 127;
    w1t[k][oc] = W1[idx];
  }
  for (int idx = t; idx < 1024; idx += 256) {
    int oc = idx >> 5, k = idx & 31;
    w2t[k][oc] = W2[idx];
  }
  if (t < 96) w3t[t & 31][t >> 5] = W3[t];

  int g = lane >> 4, li = lane & 15;
  int c = li * 8;
  f32x2 xr2[4], we2[4], at2[4];
  {
    size_t nn = active ? (size_t)n : 0;
    uint4 xrr = *(const uint4*)(xr + nn * 128 + c);
    xr2[0] = f32x2{bflo(xrr.x), bfhi(xrr.x)};
    xr2[1] = f32x2{bflo(xrr.y), bfhi(xrr.y)};
    xr2[2] = f32x2{bflo(xrr.z), bfhi(xrr.z)};
    xr2[3] = f32x2{bflo(xrr.w), bfhi(xrr.w)};
  }
#pragma unroll
  for (int j = 0; j < 4; j++) {
    we2[j] = *(const f32x2*)(We + c + 2 * j);
    at2[j] = *(const f32x2*)(att + c + 2 * j) * 1.44269504088896f;
  }
  int rs = active ? row_ptr[n] : 0;
  int re = active ? row_ptr[n + 1] : 0;
  float s = 0.f;
  f32x2 acc2[4] = {{0.f, 0.f}, {0.f, 0.f}, {0.f, 0.f}, {0.f, 0.f}};
  int nit = (re - rs + 3) >> 2;
  int idx = rs + g;
  bool v0 = idx < re;
  unsigned int md0 = meta[idx];
  bool v1 = idx + 4 < re;
  unsigned int md1 = meta[idx + 4];
  bool v2 = idx + 8 < re;
  unsigned int md2 = meta[idx + 8];
  uint4 raw0 = *(const uint4*)(xl + (size_t)(md0 & 0xFFFFu) * 128 + c);
  uint4 raw1 = *(const uint4*)(xl + (size_t)(md1 & 0xFFFFu) * 128 + c);
  for (int it = 0; it < nit; ++it) {
    bool v3 = idx + 12 < re;
    unsigned int md3 = meta[idx + 12];
    uint4 raw2 = *(const uint4*)(xl + (size_t)(md2 & 0xFFFFu) * 128 + c);
    f32x2 xa2[4];
    xa2[0] = f32x2{bflo(raw0.x), bfhi(raw0.x)};
    xa2[1] = f32x2{bflo(raw0.y), bfhi(raw0.y)};
    xa2[2] = f32x2{bflo(raw0.z), bfhi(raw0.z)};
    xa2[3] = f32x2{bflo(raw0.w), bfhi(raw0.w)};
    float eavf = __uint_as_float(md0 & 0xffff0000u);
    f32x2 eav2 = {eavf, eavf};
    f32x2 p2 = {0.f, 0.f};
#pragma unroll
    for (int j = 0; j < 4; j++) {
      f32x2 tt = xa2[j] + xr2[j];
      tt = eav2 * we2[j] + tt;
      f32x2 u = tt * 0.2f;
      tt = __builtin_elementwise_max(tt, u);
      p2 = tt * at2[j] + p2;
    }
    float p = p2.x + p2.y;
    p = dpp_addf<0xB1>(p);
    p = dpp_addf<0x4E>(p);
    p = dpp_addf<0x141>(p);
    p = dpp_addf<0x140>(p);
    float ex = v0 ? exp2f(p) : 0.f;
    f32x2 ex2 = {ex, ex};
    s += ex;
#pragma unroll
    for (int j = 0; j < 4; j++) acc2[j] = ex2 * xa2[j] + acc2[j];
    idx += 4;
    v0 = v1; v1 = v2; v2 = v3;
    md0 = md1; md1 = md2; md2 = md3;
    raw0 = raw1; raw1 = raw2;
  }
#pragma unroll
  for (int ofs = 16; ofs <= 32; ofs <<= 1) {
    s += __shfl_xor(s, ofs);
#pragma unroll
    for (int j = 0; j < 4; j++) {
      acc2[j].x += __shfl_xor(acc2[j].x, ofs);
      acc2[j].y += __shfl_xor(acc2[j].y, ofs);
    }
  }
  if (g == 0) {
    float inv = 1.f / (s + 1e-16f);
    size_t nn = active ? (size_t)n : 0;
    uint4 rr = *(const uint4*)(resid + nn * 128 + c);
    float rv[8];
    rv[0] = bflo(rr.x); rv[1] = bfhi(rr.x);
    rv[2] = bflo(rr.y); rv[3] = bfhi(rr.y);
    rv[4] = bflo(rr.z); rv[5] = bfhi(rr.z);
    rv[6] = bflo(rr.w); rv[7] = bfhi(rr.w);
#pragma unroll
    for (int j = 0; j < 4; j++) {
      f32x2 bi = *(const f32x2*)(bias + c + 2 * j);
      float o0 = acc2[j].x * inv + bi.x + rv[2 * j];
      float o1 = acc2[j].y * inv + bi.y + rv[2 * j + 1];
      o0 = (o0 > 0.f) ? o0 : (__expf(o0) - 1.f);
      o1 = (o1 > 0.f) ? o1 : (__expf(o1) - 1.f);
      hs[wid][c + 2 * j] = o0;
      hs[wid][c + 2 * j + 1] = o1;
    }
  }
  __syncthreads();   // hs (cross-lane within wave ok, W staged cross-wave)
  // ---- mlp, per-wave: oc = lane&31, kh = lane>>5 halves the K sums ----
  int oc = lane & 31, kh = lane >> 5;
  float a1 = 0.f;
#pragma unroll 4
  for (int k = 0; k < 64; k++) a1 += hs[wid][kh * 64 + k] * w1t[kh * 64 + k][oc];
  a1 += __shfl_xor(a1, 32);
  a1 = fmaxf(a1 + b1[oc], 0.f);
  if (kh == 0) y1s[wid][oc] = a1;
  __syncthreads();
  float a2 = 0.f;
#pragma unroll
  for (int k = 0; k < 16; k++) a2 += y1s[wid][kh * 16 + k] * w2t[kh * 16 + k][oc];
  a2 += __shfl_xor(a2, 32);
  a2 = fmaxf(a2 + b2[oc], 0.f);
  if (kh == 0) y2s[wid][oc] = a2;
  __syncthreads();
  if (active && lane < 3) {
    float a3 = b3[lane];
#pragma unroll
    for (int k = 0; k < 32; k++) a3 += y2s[wid][k] * w3t[k][lane];
    outp[(size_t)n * 3 + lane] = a3;
  }
}

// ---------------------------------------------------------------------------
extern "C" void kernel_launch(void* const* d_in, const int* in_sizes, int n_in,
                              void* d_out, int out_size, void* d_ws, size_t ws_size,
                              hipStream_t stream) {
  const float* x      = (const float*)d_in[0];
  const int*   ei     = (const int*)d_in[1];
  const float* ea     = (const float*)d_in[2];
  const float* g1_Wl  = (const float*)d_in[3];
  const float* g1_bl  = (const float*)d_in[4];
  const float* g1_Wr  = (const float*)d_in[5];
  const float* g1_br  = (const float*)d_in[6];
  const float* g1_We  = (const float*)d_in[7];
  const float* g1_att = (const float*)d_in[8];
  const float* g1_bias= (const float*)d_in[9];
  const float* g2_Wl  = (const float*)d_in[10];
  const float* g2_bl  = (const float*)d_in[11];
  const float* g2_Wr  = (const float*)d_in[12];
  const float* g2_br  = (const float*)d_in[13];
  const float* g2_We  = (const float*)d_in[14];
  const float* g2_att = (const float*)d_in[15];
  const float* g2_bias= (const float*)d_in[16];
  const float* res1_W = (const float*)d_in[17];
  const float* res1_b = (const float*)d_in[18];
  const float* fc1_W  = (const float*)d_in[19];
  const float* fc1_b  = (const float*)d_in[20];
  const float* fc2_W  = (const float*)d_in[21];
  const float* fc2_b  = (const float*)d_in[22];
  const float* fc3_W  = (const float*)d_in[23];
  const float* fc3_b  = (const float*)d_in[24];
  float* out = (float*)d_out;

  int N = in_sizes[0] / 64;   // 50000
  int E = in_sizes[2];        // 800000
  int Ep = E + N;

  const int NCHUNK = 256;
  const int WBLK = 224;
  int CH = (Ep + NCHUNK - 1) / NCHUNK;
  int NB = (N + 255) >> 8;
  int Nh = NB * NCHUNK;

  char* ws = (char*)d_ws;
  size_t off = 0;
  auto carve = [&](size_t bytes) -> char* {
    char* p = ws + off;
    off = (off + bytes + 255) & ~(size_t)255;
    return p;
  };
  float* meanv    = (float*)carve(4);
  float* partials = (float*)carve(NCHUNK * 4);
  int*   blksum   = (int*)carve(64 * 4);
  int*   hist     = (int*)carve((size_t)(Nh + 1) * 4);
  int*   histoff  = (int*)carve((size_t)(Nh + 1) * 4);
  int*   row_ptr  = (int*)carve((size_t)(N + 1) * 4);
  unsigned int* binmeta = (unsigned int*)carve((size_t)Ep * 4);
  unsigned char* bindlo = (unsigned char*)carve((size_t)Ep);
  unsigned int* meta = (unsigned int*)carve((size_t)(Ep + 64) * 4);
  unsigned short* xlbf = (unsigned short*)carve((size_t)N * 128 * 2);
  unsigned short* xrbf = (unsigned short*)carve((size_t)N * 128 * 2);
  unsigned short* resh2 = (unsigned short*)carve((size_t)N * 128 * 2);
  unsigned short* hbuf = (unsigned short*)carve((size_t)N * 128 * 2);
  unsigned short* Whi = (unsigned short*)carve(57344 * 2);
  unsigned short* Wlo = (unsigned short*)carve(57344 * 2);
  (void)ws_size; (void)n_in; (void)out_size;

  prep_hist<<<WBLK + NCHUNK, 256, 0, stream>>>(
      g1_Wl, g1_Wr, res1_W, g2_Wl, g2_Wr, Whi, Wlo,
      ei, ea, hist, partials, E, Ep, CH, NB, WBLK, NCHUNK);
  int nbscan = (Nh + 4095) / 4096;
  scan_blocksum<<<nbscan, 1024, 0, stream>>>(hist, blksum, Nh);
  blkoff_mean<<<1, 128, 0, stream>>>(blksum, nbscan, partials, meanv, E,
                                     meta, Ep);
  scan_out<<<nbscan, 1024, 0, stream>>>(hist, blksum, histoff, Nh, Ep);
  int MB = (N + 63) / 64;
  scatter_gemm1<<<NCHUNK + 3 * MB, 256, 0, stream>>>(
      ei, ea, meanv, histoff, binmeta, bindlo, E, Ep, CH, NB, NCHUNK,
      x, Whi, Wlo, g1_bl, xlbf, g1_br, xrbf, res1_b, resh2, N, MB);
  bin_finalize<<<NB, 256, 0, stream>>>(binmeta, bindlo, histoff, meta,
                                       row_ptr, N, Ep, NCHUNK, NB);
  attn1_kernel<<<(N + 3) / 4, 256, 0, stream>>>(
      xlbf, xrbf, resh2, g1_We, g1_att, g1_bias, meta, row_ptr, hbuf, N);
  gemm2_mfma<<<dim3(MB, 2), 256, 0, stream>>>(
      hbuf, Whi, Wlo, g2_bl, xlbf, g2_br, xrbf, N);
  attn2_mlp<<<(N + 3) / 4, 256, 0, stream>>>(
      xlbf, xrbf, hbuf, g2_We, g2_att, g2_bias, meta, row_ptr,
      fc1_W, fc1_b, fc2_W, fc2_b, fc3_W, fc3_b, out, N);
}

// Round 19
// 228.237 us; speedup vs baseline: 1.0503x; 1.0503x over previous
//
#include <hip/hip_runtime.h>
#include <math.h>

// ---------------------------------------------------------------------------
// GATv2 localization model, node-centric CSR attention.
// R19: keep R18's scatter+gemm1 fusion (big overlap win); revert the
//      attn2+MLP fusion (it re-staged W per block and doubled attn2 time).
//      attn2 and mlp are standalone again (R17 forms).
// ---------------------------------------------------------------------------

typedef short s16x8 __attribute__((ext_vector_type(8)));
typedef float f32x4 __attribute__((ext_vector_type(4)));
typedef float f32x2 __attribute__((ext_vector_type(2)));

__device__ inline unsigned short f2bf(float x) {          // fp32 -> bf16 RNE
  unsigned int u = __float_as_uint(x);
  return (unsigned short)((u + 0x7fffu + ((u >> 16) & 1u)) >> 16);
}
__device__ inline float bf2f(unsigned short h) {
  return __uint_as_float(((unsigned int)h) << 16);
}
__device__ inline float bflo(unsigned int u) { return __uint_as_float(u << 16); }
__device__ inline float bfhi(unsigned int u) { return __uint_as_float(u & 0xffff0000u); }

template <int CTRL>
__device__ inline float dpp_addf(float x) {
  int y = __builtin_amdgcn_update_dpp(0, __float_as_int(x), CTRL, 0xf, 0xf, false);
  return x + __int_as_float(y);
}

// ---------------- fused: W bf16-split (blocks < WBLK) + histogram ----------
__global__ __launch_bounds__(256) void prep_hist(
    const float* __restrict__ g1wl, const float* __restrict__ g1wr,
    const float* __restrict__ res1w, const float* __restrict__ g2wl,
    const float* __restrict__ g2wr,
    unsigned short* __restrict__ hi, unsigned short* __restrict__ lo,
    const int* __restrict__ ei, const float* __restrict__ ea,
    int* __restrict__ hist, float* __restrict__ partials,
    int E, int Ep, int CH, int NB, int WBLK, int NCHUNK) {
  int t = threadIdx.x;
  if (blockIdx.x < WBLK) {
    int i = blockIdx.x * 256 + t;
    if (i >= 57344) return;
    float f;
    if (i < 8192) f = g1wl[i];
    else if (i < 16384) f = g1wr[i - 8192];
    else if (i < 24576) f = res1w[i - 16384];
    else if (i < 40960) f = g2wl[i - 24576];
    else f = g2wr[i - 40960];
    unsigned short h = f2bf(f);
    hi[i] = h;
    lo[i] = f2bf(f - bf2f(h));
    return;
  }
  __shared__ int h[256];
  __shared__ float red[256];
  int c = blockIdx.x - WBLK;
  h[t] = 0;
  float s = 0.f;
  __syncthreads();
  int s0 = c * CH, e_ = min(Ep, s0 + CH);
  for (int e = s0 + t; e < e_; e += 256) {
    int d;
    if (e < E) { d = ei[E + e]; s += ea[e]; }
    else       { d = e - E; }
    atomicAdd(&h[d >> 8], 1);
  }
  red[t] = s;
  __syncthreads();
  for (int ofs = 128; ofs > 0; ofs >>= 1) {
    if (t < ofs) red[t] += red[t + ofs];
    __syncthreads();
  }
  if (t == 0) partials[c] = red[0];
  for (int k = t; k < NB; k += 256) hist[(size_t)k * NCHUNK + c] = h[k];
}

// ---------------- scan stage 1: per-block sums -----------------------------
__global__ __launch_bounds__(1024) void scan_blocksum(
    const int* __restrict__ in, int* __restrict__ blksum, int n) {
  __shared__ int ws[16];
  int t = threadIdx.x;
  int base = blockIdx.x * 4096 + t * 4;
  int s = 0;
  if (base + 3 < n) {
    int4 v = *(const int4*)(in + base);
    s = v.x + v.y + v.z + v.w;
  } else {
    for (int i = 0; i < 4; i++) if (base + i < n) s += in[base + i];
  }
  int lane = t & 63, w = t >> 6;
#pragma unroll
  for (int ofs = 1; ofs < 64; ofs <<= 1) s += __shfl_xor(s, ofs);
  if (lane == 0) ws[w] = s;
  __syncthreads();
  if (t == 0) {
    int tot = 0;
#pragma unroll
    for (int i = 0; i < 16; i++) tot += ws[i];
    blksum[blockIdx.x] = tot;
  }
}

// ---------------- fused: blkoff scan + mean finalize + meta pad ------------
__global__ __launch_bounds__(128) void blkoff_mean(
    int* __restrict__ blksum, int nb,
    const float* __restrict__ partials, float* __restrict__ meanv, int E,
    unsigned int* __restrict__ meta, int Ep) {
  int t = threadIdx.x;
  if (t < 64) {
    int v = (t < nb) ? blksum[t] : 0;
    int orig = v;
#pragma unroll
    for (int ofs = 1; ofs < 64; ofs <<= 1) {
      int u = __shfl_up(v, ofs);
      if (t >= ofs) v += u;
    }
    if (t < nb) blksum[t] = v - orig;
    meta[Ep + t] = 0u;                      // pad: attn over-reads <= +64
  } else {
    int l = t - 64;
    float s = partials[l] + partials[l + 64] + partials[l + 128] + partials[l + 192];
#pragma unroll
    for (int ofs = 1; ofs < 64; ofs <<= 1) s += __shfl_xor(s, ofs);
    if (l == 0) meanv[0] = s / (float)E;
  }
}

__global__ __launch_bounds__(1024) void scan_out(
    const int* __restrict__ in, const int* __restrict__ blksum,
    int* __restrict__ out, int n, int total) {
  __shared__ int ws[16];
  int t = threadIdx.x;
  int base = blockIdx.x * 4096 + t * 4;
  int4 v = {0, 0, 0, 0};
  if (base + 3 < n) {
    v = *(const int4*)(in + base);
  } else {
    if (base + 0 < n) v.x = in[base + 0];
    if (base + 1 < n) v.y = in[base + 1];
    if (base + 2 < n) v.z = in[base + 2];
    if (base + 3 < n) v.w = in[base + 3];
  }
  int s = v.x + v.y + v.z + v.w;
  int lane = t & 63, w = t >> 6;
  int inc = s;
#pragma unroll
  for (int ofs = 1; ofs < 64; ofs <<= 1) {
    int u = __shfl_up(inc, ofs);
    if (lane >= ofs) inc += u;
  }
  if (lane == 63) ws[w] = inc;
  __syncthreads();
  int waveoff = 0;
#pragma unroll
  for (int i = 0; i < 16; i++) waveoff += (i < w) ? ws[i] : 0;
  int excl = blksum[blockIdx.x] + waveoff + inc - s;
  int p0 = excl, p1 = p0 + v.x, p2 = p1 + v.y, p3 = p2 + v.z;
  if (base + 0 < n) out[base + 0] = p0;
  if (base + 1 < n) out[base + 1] = p1;
  if (base + 2 < n) out[base + 2] = p2;
  if (base + 3 < n) out[base + 3] = p3;
  if (blockIdx.x == 0 && t == 0) out[n] = total;
}

// ---------------- fused: bin_scatter (blocks<NCHUNK) + gemm1 ---------------
__global__ __launch_bounds__(256) void scatter_gemm1(
    const int* __restrict__ ei, const float* __restrict__ ea,
    const float* __restrict__ meanv, const int* __restrict__ histoff,
    unsigned int* __restrict__ binmeta, unsigned char* __restrict__ bindlo,
    int E, int Ep, int CH, int NB, int NCHUNK,
    const float* __restrict__ X,
    const unsigned short* __restrict__ Whi_all, const unsigned short* __restrict__ Wlo_all,
    const float* __restrict__ b0, unsigned short* __restrict__ o0,
    const float* __restrict__ b1, unsigned short* __restrict__ o1,
    const float* __restrict__ b2, unsigned short* __restrict__ o2,
    int N, int MB) {
  __shared__ unsigned short Xhi[64 * 64];
  __shared__ unsigned short Xlo[64 * 64];
  __shared__ int off[256];
  int t = threadIdx.x;
  if ((int)blockIdx.x < NCHUNK) {
    int c = blockIdx.x;
    for (int k = t; k < NB; k += 256) off[k] = histoff[(size_t)k * NCHUNK + c];
    __syncthreads();
    int s = c * CH, e_ = min(Ep, s + CH);
    for (int e = s + t; e < e_; e += 256) {
      int d, src; float eav;
      if (e < E) { src = ei[e]; d = ei[E + e]; eav = ea[e]; }
      else       { src = d = e - E; eav = meanv[0]; }
      int pos = atomicAdd(&off[d >> 8], 1);
      binmeta[pos] = (unsigned int)src | ((unsigned int)f2bf(eav) << 16);
      bindlo[pos] = (unsigned char)(d & 255);
    }
    return;
  }
  constexpr int K = 64;
  constexpr int KS = 2;
  int gb = blockIdx.x - NCHUNK;
  int which = gb / MB;
  int m0 = (gb % MB) * 64;
  int woff = which * 8192;
  const float* bias = (which == 0) ? b0 : (which == 1) ? b1 : b2;
  unsigned short* out = (which == 0) ? o0 : (which == 1) ? o1 : o2;
#pragma unroll
  for (int i = 0; i < 4; ++i) {
    int idx4 = t + i * 256;
    int row = idx4 / 16, k4 = idx4 % 16;
    int gm = m0 + row;
    float4 v = (gm < N) ? *(const float4*)(X + (size_t)gm * K + k4 * 4)
                        : float4{0.f, 0.f, 0.f, 0.f};
    float f[4] = {v.x, v.y, v.z, v.w};
    ushort4 h, l;
    unsigned short* hp = (unsigned short*)&h;
    unsigned short* lp = (unsigned short*)&l;
#pragma unroll
    for (int j = 0; j < 4; ++j) {
      unsigned short hb = f2bf(f[j]);
      hp[j] = hb;
      lp[j] = f2bf(f[j] - bf2f(hb));
    }
    int us = (row * K + k4 * 4) ^ ((row & 7) << 3);
    *(ushort4*)&Xhi[us] = h;
    *(ushort4*)&Xlo[us] = l;
  }
  int wv = t >> 6, lane = t & 63;
  int lr = lane & 15, kg = lane >> 4;
  s16x8 Whf[2][KS], Wlf[2][KS];
  const unsigned short* Wh = Whi_all + woff;
  const unsigned short* Wl = Wlo_all + woff;
#pragma unroll
  for (int ni = 0; ni < 2; ++ni)
#pragma unroll
    for (int ks = 0; ks < KS; ++ks) {
      int widx = (wv * 32 + ni * 16 + lr) * K + ks * 32 + kg * 8;
      Whf[ni][ks] = *(const s16x8*)(Wh + widx);
      Wlf[ni][ks] = *(const s16x8*)(Wl + widx);
    }
  __syncthreads();
  f32x4 acc[4][2] = {};
#pragma unroll
  for (int ks = 0; ks < KS; ++ks)
#pragma unroll
    for (int mi = 0; mi < 4; ++mi) {
      int r = mi * 16 + lr;
      int us = (r * K + ks * 32 + kg * 8) ^ ((r & 7) << 3);
      s16x8 ah = *(const s16x8*)&Xhi[us];
      s16x8 al = *(const s16x8*)&Xlo[us];
#pragma unroll
      for (int ni = 0; ni < 2; ++ni) {
        acc[mi][ni] = __builtin_amdgcn_mfma_f32_16x16x32_bf16(ah, Whf[ni][ks], acc[mi][ni], 0, 0, 0);
        acc[mi][ni] = __builtin_amdgcn_mfma_f32_16x16x32_bf16(ah, Wlf[ni][ks], acc[mi][ni], 0, 0, 0);
        acc[mi][ni] = __builtin_amdgcn_mfma_f32_16x16x32_bf16(al, Whf[ni][ks], acc[mi][ni], 0, 0, 0);
      }
    }
#pragma unroll
  for (int ni = 0; ni < 2; ++ni) {
    int col = wv * 32 + ni * 16 + lr;
    float bv = bias[col];
#pragma unroll
    for (int mi = 0; mi < 4; ++mi)
#pragma unroll
      for (int j = 0; j < 4; ++j) {
        int gm = m0 + mi * 16 + kg * 4 + j;
        if (gm < N) out[(size_t)gm * 128 + col] = f2bf(acc[mi][ni][j] + bv);
      }
  }
}

// ---------------- pass 2: per-bin finalize (row_ptr + in-bin sort) ---------
__global__ __launch_bounds__(256) void bin_finalize(
    const unsigned int* __restrict__ binmeta, const unsigned char* __restrict__ bindlo,
    const int* __restrict__ histoff, unsigned int* __restrict__ meta,
    int* __restrict__ row_ptr, int N, int Ep, int NCHUNK, int NB) {
  __shared__ int cntl[256];
  __shared__ int ws4[4];
  int t = threadIdx.x, k = blockIdx.x;
  int kstart = histoff[(size_t)k * NCHUNK];
  int kend = (k == NB - 1) ? Ep : histoff[(size_t)(k + 1) * NCHUNK];
  cntl[t] = 0;
  __syncthreads();
  for (int i = kstart + t; i < kend; i += 256) atomicAdd(&cntl[bindlo[i]], 1);
  __syncthreads();
  int v = cntl[t];
  int lane = t & 63, w = t >> 6;
  int inc = v;
#pragma unroll
  for (int ofs = 1; ofs < 64; ofs <<= 1) {
    int u = __shfl_up(inc, ofs);
    if (lane >= ofs) inc += u;
  }
  if (lane == 63) ws4[w] = inc;
  __syncthreads();
  int waveoff = 0;
#pragma unroll
  for (int i = 0; i < 4; i++) waveoff += (i < w) ? ws4[i] : 0;
  int base = kstart + waveoff + inc - v;
  int gd = k * 256 + t;
  if (gd < N) row_ptr[gd] = base;
  if (k == 0 && t == 0) row_ptr[N] = Ep;
  __syncthreads();
  cntl[t] = base;
  __syncthreads();
  for (int i = kstart + t; i < kend; i += 256) {
    int d = bindlo[i];
    int pos = atomicAdd(&cntl[d], 1);
    meta[pos] = binmeta[i];
  }
}

// ---------------- GEMM2 (bf16 in, M-tile 64, 2-pass) -----------------------
__global__ __launch_bounds__(256) void gemm2_mfma(
    const unsigned short* __restrict__ X,
    const unsigned short* __restrict__ Whi_all, const unsigned short* __restrict__ Wlo_all,
    const float* __restrict__ b0, unsigned short* __restrict__ o0,
    const float* __restrict__ b1, unsigned short* __restrict__ o1,
    int N) {
  constexpr int K = 128;
  constexpr int KS = 4;
  __shared__ unsigned short Xs[64 * K];
  int t = threadIdx.x;
  int m0 = blockIdx.x * 64;
  int which = blockIdx.y;
  int woff = 24576 + which * 16384;
  const float* bias = which ? b1 : b0;
  unsigned short* out = which ? o1 : o0;
#pragma unroll
  for (int i = 0; i < 4; ++i) {
    int idx8 = t + i * 256;
    int row = idx8 / 16, k8 = idx8 % 16;
    int gm = m0 + row;
    uint4 v = (gm < N) ? *(const uint4*)(X + (size_t)gm * K + k8 * 8)
                       : uint4{0u, 0u, 0u, 0u};
    int us = (row * K + k8 * 8) ^ ((row & 7) << 3);
    *(uint4*)&Xs[us] = v;
  }
  int wv = t >> 6, lane = t & 63;
  int lr = lane & 15, kg = lane >> 4;
  s16x8 Whf[2][KS], Wlf[2][KS];
  const unsigned short* Wh = Whi_all + woff;
  const unsigned short* Wl = Wlo_all + woff;
#pragma unroll
  for (int ni = 0; ni < 2; ++ni)
#pragma unroll
    for (int ks = 0; ks < KS; ++ks) {
      int widx = (wv * 32 + ni * 16 + lr) * K + ks * 32 + kg * 8;
      Whf[ni][ks] = *(const s16x8*)(Wh + widx);
      Wlf[ni][ks] = *(const s16x8*)(Wl + widx);
    }
  __syncthreads();
  f32x4 acc[4][2] = {};
#pragma unroll
  for (int ks = 0; ks < KS; ++ks)
#pragma unroll
    for (int mi = 0; mi < 4; ++mi) {
      int r = mi * 16 + lr;
      int us = (r * K + ks * 32 + kg * 8) ^ ((r & 7) << 3);
      s16x8 ah = *(const s16x8*)&Xs[us];
#pragma unroll
      for (int ni = 0; ni < 2; ++ni) {
        acc[mi][ni] = __builtin_amdgcn_mfma_f32_16x16x32_bf16(ah, Whf[ni][ks], acc[mi][ni], 0, 0, 0);
        acc[mi][ni] = __builtin_amdgcn_mfma_f32_16x16x32_bf16(ah, Wlf[ni][ks], acc[mi][ni], 0, 0, 0);
      }
    }
#pragma unroll
  for (int ni = 0; ni < 2; ++ni) {
    int col = wv * 32 + ni * 16 + lr;
    float bv = bias[col];
#pragma unroll
    for (int mi = 0; mi < 4; ++mi)
#pragma unroll
      for (int j = 0; j < 4; ++j) {
        int gm = m0 + mi * 16 + kg * 4 + j;
        if (gm < N) out[(size_t)gm * 128 + col] = f2bf(acc[mi][ni][j] + bv);
      }
  }
}

// ---------------- attention: 4 edge-parallel groups of 16 lanes ------------
template <int RED>
__global__ __launch_bounds__(256) void attn_kernel(
    const unsigned short* __restrict__ xl, const unsigned short* __restrict__ xr,
    const unsigned short* __restrict__ resid, const float* __restrict__ We,
    const float* __restrict__ att, const float* __restrict__ bias,
    const unsigned int* __restrict__ meta, const int* __restrict__ row_ptr,
    unsigned short* __restrict__ outbuf, int N) {
  int wid = threadIdx.x >> 6;
  int lane = threadIdx.x & 63;
  int n = blockIdx.x * 4 + wid;
  if (n >= N) return;
  int g = lane >> 4, li = lane & 15;
  int c = li * 8;
  f32x2 xr2[4], we2[4], at2[4];
  {
    uint4 xrr = *(const uint4*)(xr + (size_t)n * 128 + c);
    xr2[0] = f32x2{bflo(xrr.x), bfhi(xrr.x)};
    xr2[1] = f32x2{bflo(xrr.y), bfhi(xrr.y)};
    xr2[2] = f32x2{bflo(xrr.z), bfhi(xrr.z)};
    xr2[3] = f32x2{bflo(xrr.w), bfhi(xrr.w)};
  }
#pragma unroll
  for (int j = 0; j < 4; j++) {
    we2[j] = *(const f32x2*)(We + c + 2 * j);
    at2[j] = *(const f32x2*)(att + c + 2 * j) * 1.44269504088896f;  // log2(e)
  }
  int rs = row_ptr[n], re = row_ptr[n + 1];
  float s = 0.f;
  f32x2 acc2[4] = {{0.f, 0.f}, {0.f, 0.f}, {0.f, 0.f}, {0.f, 0.f}};
  int nit = (re - rs + 3) >> 2;
  int idx = rs + g;
  bool v0 = idx < re;
  unsigned int md0 = meta[idx];          // padded: safe unconditional
  bool v1 = idx + 4 < re;
  unsigned int md1 = meta[idx + 4];
  bool v2 = idx + 8 < re;
  unsigned int md2 = meta[idx + 8];
  uint4 raw0 = *(const uint4*)(xl + (size_t)(md0 & 0xFFFFu) * 128 + c);
  uint4 raw1 = *(const uint4*)(xl + (size_t)(md1 & 0xFFFFu) * 128 + c);
  for (int it = 0; it < nit; ++it) {
    bool v3 = idx + 12 < re;
    unsigned int md3 = meta[idx + 12];
    uint4 raw2 = *(const uint4*)(xl + (size_t)(md2 & 0xFFFFu) * 128 + c);
    f32x2 xa2[4];
    xa2[0] = f32x2{bflo(raw0.x), bfhi(raw0.x)};
    xa2[1] = f32x2{bflo(raw0.y), bfhi(raw0.y)};
    xa2[2] = f32x2{bflo(raw0.z), bfhi(raw0.z)};
    xa2[3] = f32x2{bflo(raw0.w), bfhi(raw0.w)};
    float eavf = __uint_as_float(md0 & 0xffff0000u);
    f32x2 eav2 = {eavf, eavf};
    f32x2 p2 = {0.f, 0.f};
#pragma unroll
    for (int j = 0; j < 4; j++) {
      f32x2 t = xa2[j] + xr2[j];
      t = eav2 * we2[j] + t;
      f32x2 u = t * 0.2f;
      t = __builtin_elementwise_max(t, u);
      p2 = t * at2[j] + p2;
    }
    float p = p2.x + p2.y;
    p = dpp_addf<0xB1>(p);
    p = dpp_addf<0x4E>(p);
    if (RED == 16) {
      p = dpp_addf<0x141>(p);
      p = dpp_addf<0x140>(p);
    }
    float ex = v0 ? exp2f(p) : 0.f;
    f32x2 ex2 = {ex, ex};
    s += ex;
#pragma unroll
    for (int j = 0; j < 4; j++) acc2[j] = ex2 * xa2[j] + acc2[j];
    idx += 4;
    v0 = v1; v1 = v2; v2 = v3;
    md0 = md1; md1 = md2; md2 = md3;
    raw0 = raw1; raw1 = raw2;
  }
#pragma unroll
  for (int ofs = 16; ofs <= 32; ofs <<= 1) {
    s += __shfl_xor(s, ofs);
#pragma unroll
    for (int j = 0; j < 4; j++) {
      acc2[j].x += __shfl_xor(acc2[j].x, ofs);
      acc2[j].y += __shfl_xor(acc2[j].y, ofs);
    }
  }
  if (g == 0) {
    float inv = 1.f / (s + 1e-16f);
    uint4 rr = *(const uint4*)(resid + (size_t)n * 128 + c);
    float rv[8];
    rv[0] = bflo(rr.x); rv[1] = bfhi(rr.x);
    rv[2] = bflo(rr.y); rv[3] = bfhi(rr.y);
    rv[4] = bflo(rr.z); rv[5] = bfhi(rr.z);
    rv[6] = bflo(rr.w); rv[7] = bfhi(rr.w);
    float o[8];
#pragma unroll
    for (int j = 0; j < 4; j++) {
      f32x2 bi = *(const f32x2*)(bias + c + 2 * j);
      o[2 * j]     = acc2[j].x * inv + bi.x + rv[2 * j];
      o[2 * j + 1] = acc2[j].y * inv + bi.y + rv[2 * j + 1];
    }
#pragma unroll
    for (int j = 0; j < 8; j++) o[j] = (o[j] > 0.f) ? o[j] : (__expf(o[j]) - 1.f);
    uint4 pk;
    pk.x = (unsigned int)f2bf(o[0]) | ((unsigned int)f2bf(o[1]) << 16);
    pk.y = (unsigned int)f2bf(o[2]) | ((unsigned int)f2bf(o[3]) << 16);
    pk.z = (unsigned int)f2bf(o[4]) | ((unsigned int)f2bf(o[5]) << 16);
    pk.w = (unsigned int)f2bf(o[6]) | ((unsigned int)f2bf(o[7]) << 16);
    *(uint4*)(outbuf + (size_t)n * 128 + c) = pk;
  }
}

// ---------------- fused MLP head: 32 nodes/block, 1024 threads -------------
__global__ __launch_bounds__(1024) void mlp_kernel(
    const unsigned short* __restrict__ h2,
    const float* __restrict__ W1, const float* __restrict__ b1,
    const float* __restrict__ W2, const float* __restrict__ b2,
    const float* __restrict__ W3, const float* __restrict__ b3,
    float* __restrict__ out, int N) {
  __shared__ float w1t[128][33];
  __shared__ float w2t[32][33];
  __shared__ float w3t[32][4];
  __shared__ float hs[32][132];
  __shared__ float y1s[32][33];
  __shared__ float y2s[32][33];
  int t = threadIdx.x;
  int n0 = blockIdx.x * 32;
  for (int idx = t; idx < 4096; idx += 1024) {
    int oc = idx >> 7, k = idx & 127;
    w1t[k][oc] = W1[idx];
  }
  {
    int oc = t >> 5, k = t & 31;
    if (t < 1024) w2t[k][oc] = W2[t];
  }
  if (t < 96) {
    int oc = t >> 5, k = t & 31;
    w3t[k][oc] = W3[t];
  }
  if (t < 512) {
    int nl = t >> 4, k8 = t & 15;
    int gm = n0 + nl;
    uint4 v = (gm < N) ? *(const uint4*)(h2 + (size_t)gm * 128 + k8 * 8)
                       : uint4{0u, 0u, 0u, 0u};
    float* hp = &hs[nl][k8 * 8];
    hp[0] = bflo(v.x); hp[1] = bfhi(v.x);
    hp[2] = bflo(v.y); hp[3] = bfhi(v.y);
    hp[4] = bflo(v.z); hp[5] = bfhi(v.z);
    hp[6] = bflo(v.w); hp[7] = bfhi(v.w);
  }
  __syncthreads();
  int nl = t >> 5, oc = t & 31;
  int n = n0 + nl;
  float acc = b1[oc];
#pragma unroll 8
  for (int k = 0; k < 128; k++) acc += hs[nl][k] * w1t[k][oc];
  y1s[nl][oc] = fmaxf(acc, 0.f);
  float acc2 = b2[oc];
#pragma unroll
  for (int k = 0; k < 32; k++) acc2 += y1s[nl][k] * w2t[k][oc];
  y2s[nl][oc] = fmaxf(acc2, 0.f);
  if (oc < 3 && n < N) {
    float acc3 = b3[oc];
#pragma unroll
    for (int k = 0; k < 32; k++) acc3 += y2s[nl][k] * w3t[k][oc];
    out[(size_t)n * 3 + oc] = acc3;
  }
}

// ---------------------------------------------------------------------------
extern "C" void kernel_launch(void* const* d_in, const int* in_sizes, int n_in,
                              void* d_out, int out_size, void* d_ws, size_t ws_size,
                              hipStream_t stream) {
  const float* x      = (const float*)d_in[0];
  const int*   ei     = (const int*)d_in[1];
  const float* ea     = (const float*)d_in[2];
  const float* g1_Wl  = (const float*)d_in[3];
  const float* g1_bl  = (const float*)d_in[4];
  const float* g1_Wr  = (const float*)d_in[5];
  const float* g1_br  = (const float*)d_in[6];
  const float* g1_We  = (const float*)d_in[7];
  const float* g1_att = (const float*)d_in[8];
  const float* g1_bias= (const float*)d_in[9];
  const float* g2_Wl  = (const float*)d_in[10];
  const float* g2_bl  = (const float*)d_in[11];
  const float* g2_Wr  = (const float*)d_in[12];
  const float* g2_br  = (const float*)d_in[13];
  const float* g2_We  = (const float*)d_in[14];
  const float* g2_att = (const float*)d_in[15];
  const float* g2_bias= (const float*)d_in[16];
  const float* res1_W = (const float*)d_in[17];
  const float* res1_b = (const float*)d_in[18];
  const float* fc1_W  = (const float*)d_in[19];
  const float* fc1_b  = (const float*)d_in[20];
  const float* fc2_W  = (const float*)d_in[21];
  const float* fc2_b  = (const float*)d_in[22];
  const float* fc3_W  = (const float*)d_in[23];
  const float* fc3_b  = (const float*)d_in[24];
  float* out = (float*)d_out;

  int N = in_sizes[0] / 64;   // 50000
  int E = in_sizes[2];        // 800000
  int Ep = E + N;

  const int NCHUNK = 256;
  const int WBLK = 224;
  int CH = (Ep + NCHUNK - 1) / NCHUNK;
  int NB = (N + 255) >> 8;
  int Nh = NB * NCHUNK;

  char* ws = (char*)d_ws;
  size_t off = 0;
  auto carve = [&](size_t bytes) -> char* {
    char* p = ws + off;
    off = (off + bytes + 255) & ~(size_t)255;
    return p;
  };
  float* meanv    = (float*)carve(4);
  float* partials = (float*)carve(NCHUNK * 4);
  int*   blksum   = (int*)carve(64 * 4);
  int*   hist     = (int*)carve((size_t)(Nh + 1) * 4);
  int*   histoff  = (int*)carve((size_t)(Nh + 1) * 4);
  int*   row_ptr  = (int*)carve((size_t)(N + 1) * 4);
  unsigned int* binmeta = (unsigned int*)carve((size_t)Ep * 4);
  unsigned char* bindlo = (unsigned char*)carve((size_t)Ep);
  unsigned int* meta = (unsigned int*)carve((size_t)(Ep + 64) * 4);
  unsigned short* xlbf = (unsigned short*)carve((size_t)N * 128 * 2);
  unsigned short* xrbf = (unsigned short*)carve((size_t)N * 128 * 2);
  unsigned short* resh2 = (unsigned short*)carve((size_t)N * 128 * 2);
  unsigned short* hbuf = (unsigned short*)carve((size_t)N * 128 * 2);
  unsigned short* Whi = (unsigned short*)carve(57344 * 2);
  unsigned short* Wlo = (unsigned short*)carve(57344 * 2);
  (void)ws_size; (void)n_in; (void)out_size;

  prep_hist<<<WBLK + NCHUNK, 256, 0, stream>>>(
      g1_Wl, g1_Wr, res1_W, g2_Wl, g2_Wr, Whi, Wlo,
      ei, ea, hist, partials, E, Ep, CH, NB, WBLK, NCHUNK);
  int nbscan = (Nh + 4095) / 4096;
  scan_blocksum<<<nbscan, 1024, 0, stream>>>(hist, blksum, Nh);
  blkoff_mean<<<1, 128, 0, stream>>>(blksum, nbscan, partials, meanv, E,
                                     meta, Ep);
  scan_out<<<nbscan, 1024, 0, stream>>>(hist, blksum, histoff, Nh, Ep);
  int MB = (N + 63) / 64;
  scatter_gemm1<<<NCHUNK + 3 * MB, 256, 0, stream>>>(
      ei, ea, meanv, histoff, binmeta, bindlo, E, Ep, CH, NB, NCHUNK,
      x, Whi, Wlo, g1_bl, xlbf, g1_br, xrbf, res1_b, resh2, N, MB);
  bin_finalize<<<NB, 256, 0, stream>>>(binmeta, bindlo, histoff, meta,
                                       row_ptr, N, Ep, NCHUNK, NB);
  attn_kernel<4><<<(N + 3) / 4, 256, 0, stream>>>(
      xlbf, xrbf, resh2, g1_We, g1_att, g1_bias, meta, row_ptr, hbuf, N);
  gemm2_mfma<<<dim3(MB, 2), 256, 0, stream>>>(
      hbuf, Whi, Wlo, g2_bl, xlbf, g2_br, xrbf, N);
  attn_kernel<16><<<(N + 3) / 4, 256, 0, stream>>>(
      xlbf, xrbf, hbuf, g2_We, g2_att, g2_bias, meta, row_ptr, resh2, N);
  mlp_kernel<<<(N + 31) / 32, 1024, 0, stream>>>(resh2, fc1_W, fc1_b, fc2_W,
                                                 fc2_b, fc3_W, fc3_b, out, N);
}